// Round 2
// baseline (3086.450 us; speedup 1.0000x reference)
//
#include <hip/hip_runtime.h>
#include <hip/hip_bf16.h>

// ---------------- constants ----------------
#define Bb    8
#define IMG   224
#define Hp    14
#define Np    196      // tokens per image
#define D4    128
#define D8    256
#define EMB   512
#define HEADS 8
#define RPEL  729
#define DEPTH 24
#define EPS   1e-5f

constexpr int EPI_NONE = 0, EPI_BIAS = 1, EPI_BIAS_GELU = 2, EPI_BIAS_RES = 3, EPI_ATOMIC = 4;

typedef __bf16 bf16x8 __attribute__((ext_vector_type(8)));
typedef float  f32x4  __attribute__((ext_vector_type(4)));

// async global->LDS, 16B per lane. LDS dest = wave-uniform base + lane*16.
static __device__ __forceinline__ void gload16(const void* g, void* l) {
    __builtin_amdgcn_global_load_lds(
        (const __attribute__((address_space(1))) void*)g,
        (__attribute__((address_space(3))) void*)l, 16, 0, 0);
}

// ================= conv 4x4/4 + patchify + per-pixel LN =================
__global__ __launch_bounds__(128) void conv_ln_kernel(
    const float* __restrict__ img, const float* __restrict__ cw,
    const float* __restrict__ cb,  const float* __restrict__ png,
    const float* __restrict__ pnb, float* __restrict__ xout)
{
    int p = blockIdx.x;                 // b*3136 + h'*56 + w'
    int b = p / 3136, rem = p % 3136;
    int hh = rem / 56, ww = rem % 56;
    __shared__ float win[48];
    __shared__ float red[4];
    int t = threadIdx.x;
    if (t < 48) {
        int ic = t >> 4, kh = (t >> 2) & 3, kw = t & 3;
        win[t] = img[(((size_t)b*3 + ic)*224 + hh*4 + kh)*224 + ww*4 + kw];
    }
    __syncthreads();
    float acc = cb[t];
    const float* wrow = cw + (size_t)t * 48;
    #pragma unroll
    for (int r = 0; r < 48; ++r) acc += win[r] * wrow[r];
    float s = acc, ss = acc * acc;
    #pragma unroll
    for (int o = 32; o > 0; o >>= 1) { s += __shfl_xor(s, o, 64); ss += __shfl_xor(ss, o, 64); }
    int wv = t >> 6;
    if ((t & 63) == 0) { red[wv*2] = s; red[wv*2+1] = ss; }
    __syncthreads();
    s = red[0] + red[2]; ss = red[1] + red[3];
    float mean = s * (1.f/128.f);
    float rstd = rsqrtf(ss * (1.f/128.f) - mean*mean + EPS);
    float v = (acc - mean) * rstd * png[t] + pnb[t];
    int hp = hh >> 2, ih = hh & 3, wp = ww >> 2, iw = ww & 3;
    int bn = b * Np + hp * Hp + wp;
    xout[((size_t)bn*16 + ih*4 + iw)*128 + t] = v;
}

// ================= generic LayerNorm: one wave per row, f32 in -> bf16 out =================
__global__ __launch_bounds__(256) void ln_kernel(
    const float* __restrict__ x, const float* __restrict__ g,
    const float* __restrict__ b, __bf16* __restrict__ y, int M, int D)
{
    int wave = threadIdx.x >> 6, lane = threadIdx.x & 63;
    int row = blockIdx.x * 4 + wave;
    if (row >= M) return;
    const float* xr = x + (size_t)row * D;
    float s = 0.f, ss = 0.f;
    for (int i = lane; i < D; i += 64) { float v = xr[i]; s += v; ss += v*v; }
    #pragma unroll
    for (int o = 32; o > 0; o >>= 1) { s += __shfl_xor(s, o, 64); ss += __shfl_xor(ss, o, 64); }
    float inv = 1.f / (float)D;
    float mean = s * inv;
    float rstd = rsqrtf(ss * inv - mean*mean + EPS);
    __bf16* yr = y + (size_t)row * D;
    for (int i = lane; i < D; i += 64)
        yr[i] = (__bf16)((xr[i] - mean) * rstd * g[i] + b[i]);
}

// ================= merge1: gather 2x2 inner (dim128->512) + LN =================
__global__ __launch_bounds__(256) void merge1_ln_kernel(
    const float* __restrict__ x, const float* __restrict__ g,
    const float* __restrict__ b, __bf16* __restrict__ y)
{
    int wave = threadIdx.x >> 6, lane = threadIdx.x & 63;
    int row = blockIdx.x * 4 + wave;
    if (row >= 6272) return;
    int j2 = row & 1, i2 = (row >> 1) & 1, bn = row >> 2;
    float vals[8]; float s = 0.f, ss = 0.f;
    #pragma unroll
    for (int t = 0; t < 8; ++t) {
        int e = lane + t*64;
        int k = e >> 7, c = e & 127;
        int ih = 2*i2 + (k & 1), iw = 2*j2 + (k >> 1);
        float v = x[((size_t)bn*16 + ih*4 + iw)*128 + c];
        vals[t] = v; s += v; ss += v*v;
    }
    #pragma unroll
    for (int o = 32; o > 0; o >>= 1) { s += __shfl_xor(s, o, 64); ss += __shfl_xor(ss, o, 64); }
    float mean = s * (1.f/512.f);
    float rstd = rsqrtf(ss * (1.f/512.f) - mean*mean + EPS);
    __bf16* yr = y + (size_t)row * 512;
    #pragma unroll
    for (int t = 0; t < 8; ++t) {
        int e = lane + t*64;
        yr[e] = (__bf16)((vals[t] - mean) * rstd * g[e] + b[e]);
    }
}

// ================= merge2: gather 2x2 tokens (dim256->1024) + LN =================
__global__ __launch_bounds__(256) void merge2_ln_kernel(
    const float* __restrict__ x, const float* __restrict__ g,
    const float* __restrict__ b, __bf16* __restrict__ y)
{
    int wave = threadIdx.x >> 6, lane = threadIdx.x & 63;
    int row = blockIdx.x * 4 + wave;
    if (row >= 1568) return;
    float vals[16]; float s = 0.f, ss = 0.f;
    #pragma unroll
    for (int t = 0; t < 16; ++t) {
        int e = lane + t*64;
        int k = e >> 8, c = e & 255;
        float v = x[((size_t)row*4 + (k & 1)*2 + (k >> 1))*256 + c];
        vals[t] = v; s += v; ss += v*v;
    }
    #pragma unroll
    for (int o = 32; o > 0; o >>= 1) { s += __shfl_xor(s, o, 64); ss += __shfl_xor(ss, o, 64); }
    float mean = s * (1.f/1024.f);
    float rstd = rsqrtf(ss * (1.f/1024.f) - mean*mean + EPS);
    __bf16* yr = y + (size_t)row * 1024;
    #pragma unroll
    for (int t = 0; t < 16; ++t) {
        int e = lane + t*64;
        yr[e] = (__bf16)((vals[t] - mean) * rstd * g[e] + b[e]);
    }
}

// ================= transpose+convert: f32 [R][C] -> bf16 [C][R] =================
static __device__ __forceinline__ void tconv_tile(
    const float* __restrict__ in, __bf16* __restrict__ out,
    int R, int C, int tile, float (*t)[33])
{
    int tiles_c = C >> 5;
    int tr = tile / tiles_c, tc = tile - tr * tiles_c;
    int ty = threadIdx.x >> 3, tx = threadIdx.x & 7;
    const float4 v = *(const float4*)&in[(size_t)(tr*32 + ty) * C + (tc*32 + tx*4)];
    t[ty][tx*4+0] = v.x; t[ty][tx*4+1] = v.y; t[ty][tx*4+2] = v.z; t[ty][tx*4+3] = v.w;
    __syncthreads();
    __bf16 o[4];
    #pragma unroll
    for (int j = 0; j < 4; ++j) o[j] = (__bf16)t[tx*4+j][ty];
    *(uint2*)&out[(size_t)(tc*32 + ty) * R + (tr*32 + tx*4)] = *(const uint2*)o;
}

__global__ __launch_bounds__(256) void tconv_kernel(
    const float* __restrict__ in, __bf16* __restrict__ out, int R, int C)
{
    __shared__ float t[32][33];
    size_t off = (size_t)blockIdx.y * R * C;
    tconv_tile(in + off, out + off, R, C, blockIdx.x, t);
}

// all 4 weight matrices of one transformer layer (blockIdx.y = layer)
__global__ __launch_bounds__(256) void layer_tconv_kernel(
    const float* __restrict__ qkvw, const float* __restrict__ projw,
    const float* __restrict__ w1, const float* __restrict__ w2,
    __bf16* __restrict__ LW, size_t lw_stride)
{
    __shared__ float t[32][33];
    int l = blockIdx.y;
    int b = blockIdx.x;
    const float* q_ = qkvw  + (size_t)l * 786432;
    const float* p_ = projw + (size_t)l * 262144;
    const float* a_ = w1    + (size_t)l * 1048576;
    const float* c_ = w2    + (size_t)l * 1048576;
    __bf16* o = LW + (size_t)l * lw_stride;
    if (b < 768)        tconv_tile(q_, o,           512, 1536, b,        t);
    else if (b < 1024)  tconv_tile(p_, o +  786432, 512,  512, b -  768, t);
    else if (b < 2048)  tconv_tile(a_, o + 1048576, 512, 2048, b - 1024, t);
    else                tconv_tile(c_, o + 2097152, 2048, 512, b - 2048, t);
}

// ================= pipelined MFMA GEMM: C[M,N] = epi(A[M,K] @ Bt[N,K]^T) =================
// BM in {64,128}, BN fixed 128, BK=32, 256 threads / 4 waves.
// Double-buffered LDS; tile t+1 prefetched via global_load_lds while tile t computes;
// counted s_waitcnt vmcnt(L) keeps the prefetch in flight across the barrier.
// NOTE: correctness of the counted vmcnt relies on NO other VMEM ops inside the
// k-loop (no spills: keep register pressure modest; bias/Rres loads are post-loop).
template<int BM, int EPI>
__global__ __launch_bounds__(256) void gemm_kernel(
    const __bf16* __restrict__ A, const __bf16* __restrict__ Bt,
    const float* __restrict__ bias, const float* __restrict__ Rres,
    void* __restrict__ Cv, int M, int N, int K, int kChunk)
{
    constexpr int BF  = (BM == 128) ? 4 : 2;     // b-frags per wave
    constexpr int LPT = (BM == 128) ? 4 : 3;     // gload16 per k-step per wave
    constexpr int ABYTES = BM * 64;              // one A buffer (BM x 32 bf16)
    constexpr int BBYTES = 8192;                 // one B buffer (128 x 32 bf16)
    __shared__ __bf16 As[2][BM][32];             // linear (gload_lds needs it)
    __shared__ __bf16 Bs[2][128][32];
    const int tid = threadIdx.x, lane = tid & 63, wave = tid >> 6;
    const int m0 = blockIdx.y * BM, n0 = blockIdx.x << 7;
    int wm, wn;
    if constexpr (BM == 128) { wm = (wave >> 1) << 6; wn = (wave & 1) << 6; }
    else                     { wm = 0;                wn = wave << 5;       }
    const int q = lane >> 4, mr = lane & 15;
    const int kstart = blockIdx.z * kChunk;
    const int kend   = min(kstart + kChunk, K);
    const int nt     = (kend - kstart) >> 5;

    f32x4 acc[4][BF];
    #pragma unroll
    for (int i = 0; i < 4; ++i)
        #pragma unroll
        for (int j = 0; j < BF; ++j)
            acc[i][j] = (f32x4){0.f, 0.f, 0.f, 0.f};

    // per-lane staging source: chunk tid -> (row = tid>>2, 8-elem col = tid&3)
    const int crow = tid >> 2, ccol = (tid & 3) << 3;
    const __bf16* ag0 = A + (size_t)min(m0 + crow, M - 1) * K + ccol;
    const __bf16* ag1 = ag0;
    if constexpr (BM == 128)
        ag1 = A + (size_t)min(m0 + 64 + crow, M - 1) * K + ccol;
    const __bf16* bg0 = Bt + (size_t)(n0 + crow) * K + ccol;
    const __bf16* bg1 = Bt + (size_t)(n0 + 64 + crow) * K + ccol;
    char* lA = (char*)&As[0][0][0] + wave * 1024;   // wave-uniform segment base
    char* lB = (char*)&Bs[0][0][0] + wave * 1024;

#define STAGE(t_, buf_) do {                                         \
        const int k0_ = kstart + ((t_) << 5);                        \
        gload16(ag0 + k0_, lA + (buf_) * ABYTES);                    \
        if constexpr (BM == 128)                                     \
            gload16(ag1 + k0_, lA + (buf_) * ABYTES + 4096);         \
        gload16(bg0 + k0_, lB + (buf_) * BBYTES);                    \
        gload16(bg1 + k0_, lB + (buf_) * BBYTES + 4096);             \
    } while (0)

    STAGE(0, 0);
    for (int t = 0; t < nt; ++t) {
        const int cur = t & 1;
        if (t + 1 < nt) {
            STAGE(t + 1, cur ^ 1);
            asm volatile("s_waitcnt vmcnt(%0)" :: "i"(LPT) : "memory");
        } else {
            asm volatile("s_waitcnt vmcnt(0)" ::: "memory");
        }
        __builtin_amdgcn_s_barrier();           // tile t fully in LDS for all waves
        bf16x8 af[4], bfr[BF];
        #pragma unroll
        for (int i = 0; i < 4; ++i)
            af[i] = *(const bf16x8*)&As[cur][wm + i*16 + mr][q*8];
        #pragma unroll
        for (int j = 0; j < BF; ++j)
            bfr[j] = *(const bf16x8*)&Bs[cur][wn + j*16 + mr][q*8];
        #pragma unroll
        for (int i = 0; i < 4; ++i)
            #pragma unroll
            for (int j = 0; j < BF; ++j)
                acc[i][j] = __builtin_amdgcn_mfma_f32_16x16x32_bf16(af[i], bfr[j], acc[i][j], 0, 0, 0);
        asm volatile("s_waitcnt lgkmcnt(0)" ::: "memory");
        __builtin_amdgcn_s_barrier();           // all reads of buf[cur] done (t+2 overwrites it)
    }
#undef STAGE

    const bool addb = (blockIdx.z == 0);
    #pragma unroll
    for (int i = 0; i < 4; ++i) {
        #pragma unroll
        for (int j = 0; j < BF; ++j) {
            const int n = n0 + wn + j*16 + mr;
            float bv = 0.f;
            if constexpr (EPI != EPI_NONE) bv = bias[n];
            #pragma unroll
            for (int r = 0; r < 4; ++r) {
                const int m = m0 + wm + i*16 + q*4 + r;
                if (m < M) {
                    if constexpr (EPI == EPI_ATOMIC) {
                        atomicAdd(&((float*)Cv)[(size_t)m * N + n], acc[i][j][r] + (addb ? bv : 0.f));
                    } else {
                        float v = acc[i][j][r] + bv;
                        if constexpr (EPI == EPI_BIAS_GELU)
                            v = 0.5f * v * (1.f + erff(v * 0.70710678118654752f));
                        if constexpr (EPI == EPI_BIAS_RES)
                            v += Rres[(size_t)m * N + n];
                        if constexpr (EPI == EPI_BIAS || EPI == EPI_BIAS_GELU)
                            ((__bf16*)Cv)[(size_t)m * N + n] = (__bf16)v;
                        else
                            ((float*)Cv)[(size_t)m * N + n] = v;
                    }
                }
            }
        }
    }
}

// ================= MFMA fused attention (bf16 qkv input, bias via rpe gather) =================
__global__ __launch_bounds__(256) void attn_kernel(
    const __bf16* __restrict__ qkv, const float* __restrict__ tab,
    const int* __restrict__ rpe, __bf16* __restrict__ y2)
{
    __shared__ __bf16 Vt[64][232];        // V^T: [d][key]
    __shared__ __bf16 Pl[4][16][232];     // per-wave P tile [qrow][key]
    int blk = blockIdx.x;                 // b*32 + h*4 + qg
    int qg = blk & 3, h = (blk >> 2) & 7, b = blk >> 5;
    int tid = threadIdx.x;

    // ---- stage V transposed ----
    for (int i = tid; i < 196*8; i += 256) {
        int key = i >> 3, seg = i & 7;
        bf16x8 v = *(const bf16x8*)(qkv + ((size_t)(b*Np + key))*1536 + 1024 + h*64 + seg*8);
        #pragma unroll
        for (int j = 0; j < 8; ++j) Vt[seg*8 + j][key] = v[j];
    }
    {
        int d0 = tid >> 2, cs = tid & 3;
        #pragma unroll
        for (int j = 0; j < 9; ++j) Vt[d0][196 + cs*9 + j] = (__bf16)0.f;
    }
    __syncthreads();

    int lane = tid & 63, wave = tid >> 6;
    int T = qg + 4*wave;
    if (T > 12) return;
    int q = lane >> 4, mr = lane & 15;

    if (lane < 36) {
        #pragma unroll
        for (int r = 0; r < 16; ++r) Pl[wave][r][196 + lane] = (__bf16)0.f;
    }

    // ---- Q fragments ----
    int qtok = b*Np + min(T*16 + mr, 195);
    const __bf16* qp = qkv + (size_t)qtok*1536 + h*64 + q*8;
    bf16x8 aq0 = *(const bf16x8*)qp;
    bf16x8 aq1 = *(const bf16x8*)(qp + 32);

    // ---- S = Q @ K^T ----
    f32x4 sacc[13];
    #pragma unroll
    for (int nt = 0; nt < 13; ++nt) {
        int ktok = b*Np + min(nt*16 + mr, 195);
        const __bf16* kp = qkv + (size_t)ktok*1536 + 512 + h*64 + q*8;
        bf16x8 bk0 = *(const bf16x8*)kp;
        bf16x8 bk1 = *(const bf16x8*)(kp + 32);
        f32x4 z = (f32x4){0.f, 0.f, 0.f, 0.f};
        z = __builtin_amdgcn_mfma_f32_16x16x32_bf16(aq0, bk0, z, 0, 0, 0);
        sacc[nt] = __builtin_amdgcn_mfma_f32_16x16x32_bf16(aq1, bk1, z, 0, 0, 0);
    }

    // ---- bias + softmax per row ----
    #pragma unroll
    for (int r = 0; r < 4; ++r) {
        int qi = T*16 + q*4 + r;
        const int* rrow = rpe + (size_t)min(qi, 195) * 196;
        float vals[13];
        #pragma unroll
        for (int nt = 0; nt < 13; ++nt) {
            int col = nt*16 + mr;
            float bv = tab[rrow[min(col, 195)]*8 + h];
            float v = sacc[nt][r] * 0.125f + bv;
            vals[nt] = (col < 196) ? v : -3.0e38f;
        }
        float m = vals[0];
        #pragma unroll
        for (int nt = 1; nt < 13; ++nt) m = fmaxf(m, vals[nt]);
        #pragma unroll
        for (int o = 8; o > 0; o >>= 1) m = fmaxf(m, __shfl_xor(m, o, 64));
        float s = 0.f, p[13];
        #pragma unroll
        for (int nt = 0; nt < 13; ++nt) { p[nt] = __expf(vals[nt] - m); s += p[nt]; }
        #pragma unroll
        for (int o = 8; o > 0; o >>= 1) s += __shfl_xor(s, o, 64);
        float inv = 1.f / s;
        #pragma unroll
        for (int nt = 0; nt < 13; ++nt)
            Pl[wave][q*4 + r][nt*16 + mr] = (__bf16)(p[nt] * inv);
    }

    // ---- O = P @ V ----
    f32x4 oacc[4];
    #pragma unroll
    for (int nt = 0; nt < 4; ++nt) oacc[nt] = (f32x4){0.f, 0.f, 0.f, 0.f};
    #pragma unroll
    for (int ks = 0; ks < 7; ++ks) {
        bf16x8 ap = *(const bf16x8*)&Pl[wave][mr][ks*32 + q*8];
        #pragma unroll
        for (int nt = 0; nt < 4; ++nt) {
            bf16x8 bv = *(const bf16x8*)&Vt[nt*16 + mr][ks*32 + q*8];
            oacc[nt] = __builtin_amdgcn_mfma_f32_16x16x32_bf16(ap, bv, oacc[nt], 0, 0, 0);
        }
    }

    #pragma unroll
    for (int nt = 0; nt < 4; ++nt) {
        #pragma unroll
        for (int r = 0; r < 4; ++r) {
            int qi = T*16 + q*4 + r;
            if (qi < 196)
                y2[((size_t)(b*Np + qi))*512 + h*64 + nt*16 + mr] = (__bf16)oacc[nt][r];
        }
    }
}

// ================= ape add =================
__global__ __launch_bounds__(256) void add_ape_kernel(float* __restrict__ x,
                                                      const float* __restrict__ ape)
{
    int i = blockIdx.x * 256 + threadIdx.x;
    if (i < 1568*512) x[i] += ape[i % (Np*512)];
}

// ================= launcher =================
extern "C" void kernel_launch(void* const* d_in, const int* in_sizes, int n_in,
                              void* d_out, int out_size, void* d_ws, size_t ws_size,
                              hipStream_t stream)
{
    typedef const float* fp;
    fp image  = (fp)d_in[0];
    fp conv_w = (fp)d_in[1];  fp conv_b = (fp)d_in[2];
    fp pn_g   = (fp)d_in[3];  fp pn_b   = (fp)d_in[4];
    fp s1_ng  = (fp)d_in[5];  fp s1_nb  = (fp)d_in[6];
    fp s1_w1  = (fp)d_in[7];  fp s1_b1  = (fp)d_in[8];
    fp s1_w2  = (fp)d_in[9];  fp s1_b2  = (fp)d_in[10];
    fp s2_ng  = (fp)d_in[11]; fp s2_nb  = (fp)d_in[12];
    fp s2_w1  = (fp)d_in[13]; fp s2_b1  = (fp)d_in[14];
    fp s2_w2  = (fp)d_in[15]; fp s2_b2  = (fp)d_in[16];
    fp pm1_ng = (fp)d_in[17]; fp pm1_nb = (fp)d_in[18]; fp pm1_rw = (fp)d_in[19];
    fp pm2_ng = (fp)d_in[20]; fp pm2_nb = (fp)d_in[21]; fp pm2_rw = (fp)d_in[22];
    fp ape    = (fp)d_in[23];
    fp n1g    = (fp)d_in[24]; fp n1b    = (fp)d_in[25];
    fp qkvw   = (fp)d_in[26]; fp qkvb   = (fp)d_in[27];
    fp tab    = (fp)d_in[28];
    fp projw  = (fp)d_in[29]; fp projb  = (fp)d_in[30];
    fp n2g    = (fp)d_in[31]; fp n2b    = (fp)d_in[32];
    fp w1     = (fp)d_in[33]; fp b1     = (fp)d_in[34];
    fp w2     = (fp)d_in[35]; fp b2     = (fp)d_in[36];
    const int* rpe = (const int*)d_in[37];

    float*  X  = (float*)d_ws;                // 3,211,264 f32 residual
    __bf16* H  = (__bf16*)(X + 3211264);      // 9,633,792 bf16 hidden (mlp hidden / qkv)
    __bf16* Y  = H + 9633792;                 // 3,211,264 bf16 LN out / attn out
    __bf16* SW = Y + 3211264;                 // 2,129,920 bf16 stage weights (B^T)
    __bf16* LW = SW + 2129920;                // per-layer (or all-layer) bf16 weights (B^T)

    // all-layer weight hoist if workspace permits (194 MB); else per-layer (49 MB)
    const size_t LWSTRIDE = 3145728;          // bf16 elems per layer
    const size_t need_all = ((size_t)(LW - (__bf16*)d_ws)) * 2 + DEPTH * LWSTRIDE * 2;
    const bool bigLW = ws_size >= need_all;

    // ---- stage-weight transpose+convert (per run) ----
    tconv_kernel<<<dim3(48, 3),  256, 0, stream>>>(s1_w1,  SW + 0,       128, 384);
    tconv_kernel<<<dim3(48, 3),  256, 0, stream>>>(s1_w2,  SW + 147456,  384, 128);
    tconv_kernel<<<dim3(192, 3), 256, 0, stream>>>(s2_w1,  SW + 294912,  256, 768);
    tconv_kernel<<<dim3(192, 3), 256, 0, stream>>>(s2_w2,  SW + 884736,  768, 256);
    tconv_kernel<<<dim3(128, 1), 256, 0, stream>>>(pm1_rw, SW + 1474560, 512, 256);
    tconv_kernel<<<dim3(512, 1), 256, 0, stream>>>(pm2_rw, SW + 1605632, 1024, 512);
    if (bigLW)
        layer_tconv_kernel<<<dim3(3072, DEPTH), 256, 0, stream>>>(
            qkvw, projw, w1, w2, LW, LWSTRIDE);

    conv_ln_kernel<<<Bb*56*56, 128, 0, stream>>>(image, conv_w, conv_b, pn_g, pn_b, X);

    for (int t = 0; t < 3; ++t) {
        ln_kernel<<<25088/4, 256, 0, stream>>>(X, s1_ng + t*128, s1_nb + t*128, Y, 25088, 128);
        gemm_kernel<128, EPI_BIAS_GELU><<<dim3(3, 196), 256, 0, stream>>>(
            Y, SW + t*49152, s1_b1 + t*384, nullptr, H, 25088, 384, 128, 128);
        gemm_kernel<64, EPI_BIAS_RES><<<dim3(1, 392), 256, 0, stream>>>(
            H, SW + 147456 + t*49152, s1_b2 + t*128, X, X, 25088, 128, 384, 384);
    }
    merge1_ln_kernel<<<6272/4, 256, 0, stream>>>(X, pm1_ng, pm1_nb, Y);
    gemm_kernel<64, EPI_NONE><<<dim3(2, 98), 256, 0, stream>>>(
        Y, SW + 1474560, nullptr, nullptr, X, 6272, 256, 512, 512);
    for (int t = 0; t < 3; ++t) {
        ln_kernel<<<6272/4, 256, 0, stream>>>(X, s2_ng + t*256, s2_nb + t*256, Y, 6272, 256);
        gemm_kernel<128, EPI_BIAS_GELU><<<dim3(6, 49), 256, 0, stream>>>(
            Y, SW + 294912 + t*196608, s2_b1 + t*768, nullptr, H, 6272, 768, 256, 256);
        gemm_kernel<64, EPI_BIAS_RES><<<dim3(2, 98), 256, 0, stream>>>(
            H, SW + 884736 + t*196608, s2_b2 + t*256, X, X, 6272, 256, 768, 768);
    }
    merge2_ln_kernel<<<1568/4, 256, 0, stream>>>(X, pm2_ng, pm2_nb, Y);
    gemm_kernel<64, EPI_NONE><<<dim3(4, 25), 256, 0, stream>>>(
        Y, SW + 1605632, nullptr, nullptr, X, 1568, 512, 1024, 1024);
    add_ape_kernel<<<(1568*512+255)/256, 256, 0, stream>>>(X, ape);

    for (int l = 0; l < DEPTH; ++l) {
        const __bf16* LWl = bigLW ? LW + (size_t)l * LWSTRIDE : LW;
        if (!bigLW)
            layer_tconv_kernel<<<dim3(3072, 1), 256, 0, stream>>>(
                qkvw + (size_t)l*512*1536, projw + (size_t)l*512*512,
                w1 + (size_t)l*512*2048, w2 + (size_t)l*2048*512, LW, 0);
        ln_kernel<<<392, 256, 0, stream>>>(X, n1g + l*EMB, n1b + l*EMB, Y, 1568, EMB);
        // qkv: single-pass, bf16 direct write (no memset / no atomics)
        gemm_kernel<64, EPI_BIAS><<<dim3(12, 25), 256, 0, stream>>>(
            Y, LWl, qkvb + (size_t)l*1536, nullptr, H, 1568, 1536, EMB, EMB);
        attn_kernel<<<256, 256, 0, stream>>>(H, tab + (size_t)l*RPEL*HEADS, rpe, Y);
        // proj: split-K x4, atomic onto residual X (res-add free)
        gemm_kernel<64, EPI_ATOMIC><<<dim3(4, 25, 4), 256, 0, stream>>>(
            Y, LWl + 786432, projb + (size_t)l*EMB, nullptr, X, 1568, EMB, EMB, 128);
        ln_kernel<<<392, 256, 0, stream>>>(X, n2g + l*EMB, n2b + l*EMB, Y, 1568, EMB);
        gemm_kernel<64, EPI_BIAS_GELU><<<dim3(16, 25), 256, 0, stream>>>(
            Y, LWl + 1048576, b1 + (size_t)l*2048, nullptr, H, 1568, 2048, EMB, EMB);
        // mlp2: split-K x4, atomic onto residual X
        gemm_kernel<64, EPI_ATOMIC><<<dim3(4, 25, 4), 256, 0, stream>>>(
            H, LWl + 2097152, b2 + (size_t)l*EMB, nullptr, X, 1568, EMB, 2048, 512);
    }
    hipMemcpyAsync(d_out, X, (size_t)1568*512*sizeof(float), hipMemcpyDeviceToDevice, stream);
}

// Round 3
// 2808.337 us; speedup vs baseline: 1.0990x; 1.0990x over previous
//
#include <hip/hip_runtime.h>
#include <hip/hip_bf16.h>

// ---------------- constants ----------------
#define Bb    8
#define IMG   224
#define Hp    14
#define Np    196      // tokens per image
#define D4    128
#define D8    256
#define EMB   512
#define HEADS 8
#define RPEL  729
#define DEPTH 24
#define EPS   1e-5f

constexpr int EPI_NONE = 0, EPI_BIAS = 1, EPI_BIAS_GELU = 2, EPI_BIAS_RES = 3, EPI_ATOMIC = 4, EPI_APE = 5;

typedef __bf16 bf16x8 __attribute__((ext_vector_type(8)));
typedef float  f32x4  __attribute__((ext_vector_type(4)));

// async global->LDS, 16B per lane. LDS dest = wave-uniform base + lane*16.
static __device__ __forceinline__ void gload16(const void* g, void* l) {
    __builtin_amdgcn_global_load_lds(
        (const __attribute__((address_space(1))) void*)g,
        (__attribute__((address_space(3))) void*)l, 16, 0, 0);
}

// ================= conv 4x4/4 + patchify + per-pixel LN =================
__global__ __launch_bounds__(128) void conv_ln_kernel(
    const float* __restrict__ img, const float* __restrict__ cw,
    const float* __restrict__ cb,  const float* __restrict__ png,
    const float* __restrict__ pnb, float* __restrict__ xout)
{
    int p = blockIdx.x;                 // b*3136 + h'*56 + w'
    int b = p / 3136, rem = p % 3136;
    int hh = rem / 56, ww = rem % 56;
    __shared__ float win[48];
    __shared__ float red[4];
    int t = threadIdx.x;
    if (t < 48) {
        int ic = t >> 4, kh = (t >> 2) & 3, kw = t & 3;
        win[t] = img[(((size_t)b*3 + ic)*224 + hh*4 + kh)*224 + ww*4 + kw];
    }
    __syncthreads();
    float acc = cb[t];
    const float* wrow = cw + (size_t)t * 48;
    #pragma unroll
    for (int r = 0; r < 48; ++r) acc += win[r] * wrow[r];
    float s = acc, ss = acc * acc;
    #pragma unroll
    for (int o = 32; o > 0; o >>= 1) { s += __shfl_xor(s, o, 64); ss += __shfl_xor(ss, o, 64); }
    int wv = t >> 6;
    if ((t & 63) == 0) { red[wv*2] = s; red[wv*2+1] = ss; }
    __syncthreads();
    s = red[0] + red[2]; ss = red[1] + red[3];
    float mean = s * (1.f/128.f);
    float rstd = rsqrtf(ss * (1.f/128.f) - mean*mean + EPS);
    float v = (acc - mean) * rstd * png[t] + pnb[t];
    int hp = hh >> 2, ih = hh & 3, wp = ww >> 2, iw = ww & 3;
    int bn = b * Np + hp * Hp + wp;
    xout[((size_t)bn*16 + ih*4 + iw)*128 + t] = v;
}

// ================= generic LayerNorm: one wave per row, f32 in -> bf16 out =================
__global__ __launch_bounds__(256) void ln_kernel(
    const float* __restrict__ x, const float* __restrict__ g,
    const float* __restrict__ b, __bf16* __restrict__ y, int M, int D)
{
    int wave = threadIdx.x >> 6, lane = threadIdx.x & 63;
    int row = blockIdx.x * 4 + wave;
    if (row >= M) return;
    const float* xr = x + (size_t)row * D;
    float s = 0.f, ss = 0.f;
    for (int i = lane; i < D; i += 64) { float v = xr[i]; s += v; ss += v*v; }
    #pragma unroll
    for (int o = 32; o > 0; o >>= 1) { s += __shfl_xor(s, o, 64); ss += __shfl_xor(ss, o, 64); }
    float inv = 1.f / (float)D;
    float mean = s * inv;
    float rstd = rsqrtf(ss * inv - mean*mean + EPS);
    __bf16* yr = y + (size_t)row * D;
    for (int i = lane; i < D; i += 64)
        yr[i] = (__bf16)((xr[i] - mean) * rstd * g[i] + b[i]);
}

// ================= merge1: gather 2x2 inner (dim128->512) + LN =================
__global__ __launch_bounds__(256) void merge1_ln_kernel(
    const float* __restrict__ x, const float* __restrict__ g,
    const float* __restrict__ b, __bf16* __restrict__ y)
{
    int wave = threadIdx.x >> 6, lane = threadIdx.x & 63;
    int row = blockIdx.x * 4 + wave;
    if (row >= 6272) return;
    int j2 = row & 1, i2 = (row >> 1) & 1, bn = row >> 2;
    float vals[8]; float s = 0.f, ss = 0.f;
    #pragma unroll
    for (int t = 0; t < 8; ++t) {
        int e = lane + t*64;
        int k = e >> 7, c = e & 127;
        int ih = 2*i2 + (k & 1), iw = 2*j2 + (k >> 1);
        float v = x[((size_t)bn*16 + ih*4 + iw)*128 + c];
        vals[t] = v; s += v; ss += v*v;
    }
    #pragma unroll
    for (int o = 32; o > 0; o >>= 1) { s += __shfl_xor(s, o, 64); ss += __shfl_xor(ss, o, 64); }
    float mean = s * (1.f/512.f);
    float rstd = rsqrtf(ss * (1.f/512.f) - mean*mean + EPS);
    __bf16* yr = y + (size_t)row * 512;
    #pragma unroll
    for (int t = 0; t < 8; ++t) {
        int e = lane + t*64;
        yr[e] = (__bf16)((vals[t] - mean) * rstd * g[e] + b[e]);
    }
}

// ================= merge2: gather 2x2 tokens (dim256->1024) + LN =================
__global__ __launch_bounds__(256) void merge2_ln_kernel(
    const float* __restrict__ x, const float* __restrict__ g,
    const float* __restrict__ b, __bf16* __restrict__ y)
{
    int wave = threadIdx.x >> 6, lane = threadIdx.x & 63;
    int row = blockIdx.x * 4 + wave;
    if (row >= 1568) return;
    float vals[16]; float s = 0.f, ss = 0.f;
    #pragma unroll
    for (int t = 0; t < 16; ++t) {
        int e = lane + t*64;
        int k = e >> 8, c = e & 255;
        float v = x[((size_t)row*4 + (k & 1)*2 + (k >> 1))*256 + c];
        vals[t] = v; s += v; ss += v*v;
    }
    #pragma unroll
    for (int o = 32; o > 0; o >>= 1) { s += __shfl_xor(s, o, 64); ss += __shfl_xor(ss, o, 64); }
    float mean = s * (1.f/1024.f);
    float rstd = rsqrtf(ss * (1.f/1024.f) - mean*mean + EPS);
    __bf16* yr = y + (size_t)row * 1024;
    #pragma unroll
    for (int t = 0; t < 16; ++t) {
        int e = lane + t*64;
        yr[e] = (__bf16)((vals[t] - mean) * rstd * g[e] + b[e]);
    }
}

// ================= transpose+convert 32x32: f32 [R][C] -> bf16 [C][R] =================
static __device__ __forceinline__ void tconv_tile(
    const float* __restrict__ in, __bf16* __restrict__ out,
    int R, int C, int tile, float (*t)[33])
{
    int tiles_c = C >> 5;
    int tr = tile / tiles_c, tc = tile - tr * tiles_c;
    int ty = threadIdx.x >> 3, tx = threadIdx.x & 7;
    const float4 v = *(const float4*)&in[(size_t)(tr*32 + ty) * C + (tc*32 + tx*4)];
    t[ty][tx*4+0] = v.x; t[ty][tx*4+1] = v.y; t[ty][tx*4+2] = v.z; t[ty][tx*4+3] = v.w;
    __syncthreads();
    __bf16 o[4];
    #pragma unroll
    for (int j = 0; j < 4; ++j) o[j] = (__bf16)t[tx*4+j][ty];
    *(uint2*)&out[(size_t)(tc*32 + ty) * R + (tr*32 + tx*4)] = *(const uint2*)o;
}

__global__ __launch_bounds__(256) void tconv_kernel(
    const float* __restrict__ in, __bf16* __restrict__ out, int R, int C)
{
    __shared__ float t[32][33];
    size_t off = (size_t)blockIdx.y * R * C;
    tconv_tile(in + off, out + off, R, C, blockIdx.x, t);
}

// ================= transpose+convert 64x64 (coalesced 128B-row writes) =================
static __device__ __forceinline__ void tconv64_tile(
    const float* __restrict__ in, __bf16* __restrict__ out,
    int R, int C, int tile, float (*t)[65])
{
    int tiles_c = C >> 6;
    int tr = tile / tiles_c, tc = tile - tr * tiles_c;
    int tid = threadIdx.x;
    int lrow = tid >> 4, lcol = (tid & 15) << 2;
    #pragma unroll
    for (int i = 0; i < 4; ++i) {
        int row = lrow + i*16;
        const float4 v = *(const float4*)&in[(size_t)(tr*64 + row) * C + (tc*64 + lcol)];
        t[row][lcol+0] = v.x; t[row][lcol+1] = v.y; t[row][lcol+2] = v.z; t[row][lcol+3] = v.w;
    }
    __syncthreads();
    int orow = tid >> 3, och = tid & 7;
    #pragma unroll
    for (int i = 0; i < 2; ++i) {
        int r = orow + i*32;
        __bf16 o[8];
        #pragma unroll
        for (int j = 0; j < 8; ++j) o[j] = (__bf16)t[och*8 + j][r];
        *(uint4*)&out[(size_t)(tc*64 + r) * R + (tr*64 + och*8)] = *(const uint4*)o;
    }
}

// all 4 weight matrices of one transformer layer (blockIdx.y = layer), 768 tiles
__global__ __launch_bounds__(256) void layer_tconv_kernel(
    const float* __restrict__ qkvw, const float* __restrict__ projw,
    const float* __restrict__ w1, const float* __restrict__ w2,
    __bf16* __restrict__ LW, size_t lw_stride)
{
    __shared__ float t[64][65];
    int l = blockIdx.y;
    int b = blockIdx.x;
    const float* q_ = qkvw  + (size_t)l * 786432;
    const float* p_ = projw + (size_t)l * 262144;
    const float* a_ = w1    + (size_t)l * 1048576;
    const float* c_ = w2    + (size_t)l * 1048576;
    __bf16* o = LW + (size_t)l * lw_stride;
    if (b < 192)       tconv64_tile(q_, o,           512, 1536, b,       t);
    else if (b < 256)  tconv64_tile(p_, o +  786432, 512,  512, b - 192, t);
    else if (b < 512)  tconv64_tile(a_, o + 1048576, 512, 2048, b - 256, t);
    else               tconv64_tile(c_, o + 2097152, 2048, 512, b - 512, t);
}

// ================= m97-class MFMA GEMM (BN=128, BK=32, single-buffer) =================
// For the large-M stage GEMMs. C[M,N] = epi(A[M,K] @ Bt[N,K]^T).
template<int BM, int EPI>
__global__ __launch_bounds__(256) void gemm_kernel(
    const __bf16* __restrict__ A, const __bf16* __restrict__ Bt,
    const float* __restrict__ bias, const float* __restrict__ Rres,
    void* __restrict__ Cv, int M, int N, int K, int kChunk)
{
    constexpr int BF = (BM == 128) ? 4 : 2;   // b-frags per wave
    __shared__ __bf16 As[BM][32];             // linear (gload_lds needs it)
    __shared__ __bf16 Bs[128][32];
    const int tid = threadIdx.x, lane = tid & 63, wave = tid >> 6;
    const int m0 = blockIdx.y * BM, n0 = blockIdx.x << 7;
    int wm, wn;
    if constexpr (BM == 128) { wm = (wave >> 1) << 6; wn = (wave & 1) << 6; }
    else                     { wm = 0;                wn = wave << 5;       }
    const int q = lane >> 4, mr = lane & 15;
    const int kstart = blockIdx.z * kChunk;
    const int kend   = min(kstart + kChunk, K);

    f32x4 acc[4][BF];
    #pragma unroll
    for (int i = 0; i < 4; ++i)
        #pragma unroll
        for (int j = 0; j < BF; ++j)
            acc[i][j] = (f32x4){0.f, 0.f, 0.f, 0.f};

    const int crow = tid >> 2, ccol = (tid & 3) << 3;
    const __bf16* ag0 = A + (size_t)min(m0 + crow, M - 1) * K + ccol;
    const __bf16* ag1 = ag0;
    if constexpr (BM == 128)
        ag1 = A + (size_t)min(m0 + 64 + crow, M - 1) * K + ccol;
    const __bf16* bg0 = Bt + (size_t)(n0 + crow) * K + ccol;
    const __bf16* bg1 = Bt + (size_t)(n0 + 64 + crow) * K + ccol;
    char* lA = (char*)&As[0][0] + wave * 1024;   // wave-uniform segment base
    char* lB = (char*)&Bs[0][0] + wave * 1024;

    for (int k0 = kstart; k0 < kend; k0 += 32) {
        gload16(ag0 + k0, lA);
        if constexpr (BM == 128) gload16(ag1 + k0, lA + 4096);
        gload16(bg0 + k0, lB);
        gload16(bg1 + k0, lB + 4096);
        __syncthreads();                          // drains vmcnt -> LDS valid
        bf16x8 af[4], bfr[BF];
        #pragma unroll
        for (int i = 0; i < 4; ++i)
            af[i] = *(const bf16x8*)&As[wm + i*16 + mr][q*8];
        #pragma unroll
        for (int j = 0; j < BF; ++j)
            bfr[j] = *(const bf16x8*)&Bs[wn + j*16 + mr][q*8];
        #pragma unroll
        for (int i = 0; i < 4; ++i)
            #pragma unroll
            for (int j = 0; j < BF; ++j)
                acc[i][j] = __builtin_amdgcn_mfma_f32_16x16x32_bf16(af[i], bfr[j], acc[i][j], 0, 0, 0);
        __syncthreads();
    }

    const bool addb = (blockIdx.z == 0);
    #pragma unroll
    for (int i = 0; i < 4; ++i) {
        #pragma unroll
        for (int j = 0; j < BF; ++j) {
            const int n = n0 + wn + j*16 + mr;
            float bv = 0.f;
            if constexpr (EPI != EPI_NONE) bv = bias[n];
            #pragma unroll
            for (int r = 0; r < 4; ++r) {
                const int m = m0 + wm + i*16 + q*4 + r;
                if (m < M) {
                    if constexpr (EPI == EPI_ATOMIC) {
                        atomicAdd(&((float*)Cv)[(size_t)m * N + n], acc[i][j][r] + (addb ? bv : 0.f));
                    } else {
                        float v = acc[i][j][r] + bv;
                        if constexpr (EPI == EPI_BIAS_GELU)
                            v = 0.5f * v * (1.f + erff(v * 0.70710678118654752f));
                        if constexpr (EPI == EPI_BIAS_RES)
                            v += Rres[(size_t)m * N + n];
                        if constexpr (EPI == EPI_BIAS || EPI == EPI_BIAS_GELU)
                            ((__bf16*)Cv)[(size_t)m * N + n] = (__bf16)v;
                        else
                            ((float*)Cv)[(size_t)m * N + n] = v;
                    }
                }
            }
        }
    }
}

// ================= small-M MFMA GEMM: 64x64 tile, BK=64, XOR-swizzled LDS =================
// Grid is 2-3x larger than the BN=128 kernel at the same problem -> co-resident
// blocks hide the per-k-step vmcnt drain (m114). LDS rows are 128B so the raw
// layout would be 16-way bank-conflicted; fix is the m201/m173 pattern: XOR the
// GLOBAL source col by ((row&7)<<3), keep gload_lds dest linear, XOR the
// ds_read col the same way. 2-way residual conflict = free (m136).
template<int EPI>
__global__ __launch_bounds__(256) void gemm64_kernel(
    const __bf16* __restrict__ A, const __bf16* __restrict__ Bt,
    const float* __restrict__ bias, const float* __restrict__ Rres,
    void* __restrict__ Cv, int M, int N, int K, int kChunk)
{
    __shared__ __bf16 As[64][64];    // 8 KB
    __shared__ __bf16 Bs[64][64];    // 8 KB
    const int tid = threadIdx.x, lane = tid & 63, wave = tid >> 6;
    const int m0 = blockIdx.y << 6, n0 = blockIdx.x << 6;
    const int wm = (wave >> 1) << 5, wn = (wave & 1) << 5;
    const int q = lane >> 4, mr = lane & 15;
    const int kstart = blockIdx.z * kChunk;
    const int kend   = min(kstart + kChunk, K);

    f32x4 acc[2][2];
    #pragma unroll
    for (int i = 0; i < 2; ++i)
        #pragma unroll
        for (int j = 0; j < 2; ++j)
            acc[i][j] = (f32x4){0.f, 0.f, 0.f, 0.f};

    // staging: slot s = tid + 256*i -> row = s>>3, col8 = s&7 (16B each)
    const int srow = tid >> 3;                       // 0..31 (slot1 adds 32)
    const int scol = ((tid & 7) << 3) ^ ((srow & 7) << 3);   // pre-swizzled source col
    const __bf16* agA = A  + (size_t)min(m0 + srow,      M - 1) * K + scol;
    const __bf16* agB = A  + (size_t)min(m0 + 32 + srow, M - 1) * K + scol;
    const __bf16* bgA = Bt + (size_t)(n0 + srow)      * K + scol;
    const __bf16* bgB = Bt + (size_t)(n0 + 32 + srow) * K + scol;
    char* lA = (char*)&As[0][0] + wave * 1024;       // wave-uniform segment base
    char* lB = (char*)&Bs[0][0] + wave * 1024;

    // swizzled read col-groups (bytes within a 128B row), h=0 / h=1 k-halves
    const int pg0 = ((q)     ^ (mr & 7)) << 4;
    const int pg1 = ((q + 4) ^ (mr & 7)) << 4;

    for (int k0 = kstart; k0 < kend; k0 += 64) {
        gload16(agA + k0, lA);
        gload16(agB + k0, lA + 4096);
        gload16(bgA + k0, lB);
        gload16(bgB + k0, lB + 4096);
        __syncthreads();                          // drains vmcnt -> LDS valid
        bf16x8 af[2][2], bfr[2][2];
        #pragma unroll
        for (int i = 0; i < 2; ++i) {
            const char* ar = (const char*)&As[wm + i*16 + mr][0];
            af[i][0] = *(const bf16x8*)(ar + pg0);
            af[i][1] = *(const bf16x8*)(ar + pg1);
        }
        #pragma unroll
        for (int j = 0; j < 2; ++j) {
            const char* br = (const char*)&Bs[wn + j*16 + mr][0];
            bfr[j][0] = *(const bf16x8*)(br + pg0);
            bfr[j][1] = *(const bf16x8*)(br + pg1);
        }
        #pragma unroll
        for (int i = 0; i < 2; ++i)
            #pragma unroll
            for (int j = 0; j < 2; ++j) {
                acc[i][j] = __builtin_amdgcn_mfma_f32_16x16x32_bf16(af[i][0], bfr[j][0], acc[i][j], 0, 0, 0);
                acc[i][j] = __builtin_amdgcn_mfma_f32_16x16x32_bf16(af[i][1], bfr[j][1], acc[i][j], 0, 0, 0);
            }
        __syncthreads();
    }

    const bool addb = (blockIdx.z == 0);
    #pragma unroll
    for (int i = 0; i < 2; ++i) {
        #pragma unroll
        for (int j = 0; j < 2; ++j) {
            const int n = n0 + wn + j*16 + mr;
            float bv = 0.f;
            if constexpr (EPI == EPI_BIAS || EPI == EPI_BIAS_GELU || EPI == EPI_BIAS_RES || EPI == EPI_ATOMIC)
                bv = bias[n];
            #pragma unroll
            for (int r = 0; r < 4; ++r) {
                const int m = m0 + wm + i*16 + q*4 + r;
                if (m < M) {
                    if constexpr (EPI == EPI_ATOMIC) {
                        atomicAdd(&((float*)Cv)[(size_t)m * N + n], acc[i][j][r] + (addb ? bv : 0.f));
                    } else {
                        float v = acc[i][j][r] + bv;
                        if constexpr (EPI == EPI_BIAS_GELU)
                            v = 0.5f * v * (1.f + erff(v * 0.70710678118654752f));
                        if constexpr (EPI == EPI_BIAS_RES)
                            v += Rres[(size_t)m * N + n];
                        if constexpr (EPI == EPI_APE)
                            v += Rres[(size_t)(m % Np) * N + n];   // ape broadcast over batch
                        if constexpr (EPI == EPI_BIAS || EPI == EPI_BIAS_GELU)
                            ((__bf16*)Cv)[(size_t)m * N + n] = (__bf16)v;
                        else
                            ((float*)Cv)[(size_t)m * N + n] = v;
                    }
                }
            }
        }
    }
}

// ================= MFMA fused attention (bf16 qkv input, bias via rpe gather) =================
__global__ __launch_bounds__(256) void attn_kernel(
    const __bf16* __restrict__ qkv, const float* __restrict__ tab,
    const int* __restrict__ rpe, __bf16* __restrict__ y2)
{
    __shared__ __bf16 Vt[64][232];        // V^T: [d][key]
    __shared__ __bf16 Pl[4][16][232];     // per-wave P tile [qrow][key]
    int blk = blockIdx.x;                 // b*32 + h*4 + qg
    int qg = blk & 3, h = (blk >> 2) & 7, b = blk >> 5;
    int tid = threadIdx.x;

    // ---- stage V transposed ----
    for (int i = tid; i < 196*8; i += 256) {
        int key = i >> 3, seg = i & 7;
        bf16x8 v = *(const bf16x8*)(qkv + ((size_t)(b*Np + key))*1536 + 1024 + h*64 + seg*8);
        #pragma unroll
        for (int j = 0; j < 8; ++j) Vt[seg*8 + j][key] = v[j];
    }
    {
        int d0 = tid >> 2, cs = tid & 3;
        #pragma unroll
        for (int j = 0; j < 9; ++j) Vt[d0][196 + cs*9 + j] = (__bf16)0.f;
    }
    __syncthreads();

    int lane = tid & 63, wave = tid >> 6;
    int T = qg + 4*wave;
    if (T > 12) return;
    int q = lane >> 4, mr = lane & 15;

    if (lane < 36) {
        #pragma unroll
        for (int r = 0; r < 16; ++r) Pl[wave][r][196 + lane] = (__bf16)0.f;
    }

    // ---- Q fragments ----
    int qtok = b*Np + min(T*16 + mr, 195);
    const __bf16* qp = qkv + (size_t)qtok*1536 + h*64 + q*8;
    bf16x8 aq0 = *(const bf16x8*)qp;
    bf16x8 aq1 = *(const bf16x8*)(qp + 32);

    // ---- S = Q @ K^T ----
    f32x4 sacc[13];
    #pragma unroll
    for (int nt = 0; nt < 13; ++nt) {
        int ktok = b*Np + min(nt*16 + mr, 195);
        const __bf16* kp = qkv + (size_t)ktok*1536 + 512 + h*64 + q*8;
        bf16x8 bk0 = *(const bf16x8*)kp;
        bf16x8 bk1 = *(const bf16x8*)(kp + 32);
        f32x4 z = (f32x4){0.f, 0.f, 0.f, 0.f};
        z = __builtin_amdgcn_mfma_f32_16x16x32_bf16(aq0, bk0, z, 0, 0, 0);
        sacc[nt] = __builtin_amdgcn_mfma_f32_16x16x32_bf16(aq1, bk1, z, 0, 0, 0);
    }

    // ---- bias + softmax per row ----
    #pragma unroll
    for (int r = 0; r < 4; ++r) {
        int qi = T*16 + q*4 + r;
        const int* rrow = rpe + (size_t)min(qi, 195) * 196;
        float vals[13];
        #pragma unroll
        for (int nt = 0; nt < 13; ++nt) {
            int col = nt*16 + mr;
            float bv = tab[rrow[min(col, 195)]*8 + h];
            float v = sacc[nt][r] * 0.125f + bv;
            vals[nt] = (col < 196) ? v : -3.0e38f;
        }
        float m = vals[0];
        #pragma unroll
        for (int nt = 1; nt < 13; ++nt) m = fmaxf(m, vals[nt]);
        #pragma unroll
        for (int o = 8; o > 0; o >>= 1) m = fmaxf(m, __shfl_xor(m, o, 64));
        float s = 0.f, p[13];
        #pragma unroll
        for (int nt = 0; nt < 13; ++nt) { p[nt] = __expf(vals[nt] - m); s += p[nt]; }
        #pragma unroll
        for (int o = 8; o > 0; o >>= 1) s += __shfl_xor(s, o, 64);
        float inv = 1.f / s;
        #pragma unroll
        for (int nt = 0; nt < 13; ++nt)
            Pl[wave][q*4 + r][nt*16 + mr] = (__bf16)(p[nt] * inv);
    }

    // ---- O = P @ V ----
    f32x4 oacc[4];
    #pragma unroll
    for (int nt = 0; nt < 4; ++nt) oacc[nt] = (f32x4){0.f, 0.f, 0.f, 0.f};
    #pragma unroll
    for (int ks = 0; ks < 7; ++ks) {
        bf16x8 ap = *(const bf16x8*)&Pl[wave][mr][ks*32 + q*8];
        #pragma unroll
        for (int nt = 0; nt < 4; ++nt) {
            bf16x8 bv = *(const bf16x8*)&Vt[nt*16 + mr][ks*32 + q*8];
            oacc[nt] = __builtin_amdgcn_mfma_f32_16x16x32_bf16(ap, bv, oacc[nt], 0, 0, 0);
        }
    }

    #pragma unroll
    for (int nt = 0; nt < 4; ++nt) {
        #pragma unroll
        for (int r = 0; r < 4; ++r) {
            int qi = T*16 + q*4 + r;
            if (qi < 196)
                y2[((size_t)(b*Np + qi))*512 + h*64 + nt*16 + mr] = (__bf16)oacc[nt][r];
        }
    }
}

// ================= launcher =================
extern "C" void kernel_launch(void* const* d_in, const int* in_sizes, int n_in,
                              void* d_out, int out_size, void* d_ws, size_t ws_size,
                              hipStream_t stream)
{
    typedef const float* fp;
    fp image  = (fp)d_in[0];
    fp conv_w = (fp)d_in[1];  fp conv_b = (fp)d_in[2];
    fp pn_g   = (fp)d_in[3];  fp pn_b   = (fp)d_in[4];
    fp s1_ng  = (fp)d_in[5];  fp s1_nb  = (fp)d_in[6];
    fp s1_w1  = (fp)d_in[7];  fp s1_b1  = (fp)d_in[8];
    fp s1_w2  = (fp)d_in[9];  fp s1_b2  = (fp)d_in[10];
    fp s2_ng  = (fp)d_in[11]; fp s2_nb  = (fp)d_in[12];
    fp s2_w1  = (fp)d_in[13]; fp s2_b1  = (fp)d_in[14];
    fp s2_w2  = (fp)d_in[15]; fp s2_b2  = (fp)d_in[16];
    fp pm1_ng = (fp)d_in[17]; fp pm1_nb = (fp)d_in[18]; fp pm1_rw = (fp)d_in[19];
    fp pm2_ng = (fp)d_in[20]; fp pm2_nb = (fp)d_in[21]; fp pm2_rw = (fp)d_in[22];
    fp ape    = (fp)d_in[23];
    fp n1g    = (fp)d_in[24]; fp n1b    = (fp)d_in[25];
    fp qkvw   = (fp)d_in[26]; fp qkvb   = (fp)d_in[27];
    fp tab    = (fp)d_in[28];
    fp projw  = (fp)d_in[29]; fp projb  = (fp)d_in[30];
    fp n2g    = (fp)d_in[31]; fp n2b    = (fp)d_in[32];
    fp w1     = (fp)d_in[33]; fp b1     = (fp)d_in[34];
    fp w2     = (fp)d_in[35]; fp b2     = (fp)d_in[36];
    const int* rpe = (const int*)d_in[37];

    float*  X  = (float*)d_ws;                // 3,211,264 f32 residual
    __bf16* H  = (__bf16*)(X + 3211264);      // 9,633,792 bf16 hidden (mlp hidden / qkv)
    __bf16* Y  = H + 9633792;                 // 3,211,264 bf16 LN out / attn out
    __bf16* SW = Y + 3211264;                 // 2,129,920 bf16 stage weights (B^T)
    __bf16* LW = SW + 2129920;                // per-layer (or all-layer) bf16 weights (B^T)

    // all-layer weight hoist if workspace permits (194 MB); else per-layer (49 MB)
    const size_t LWSTRIDE = 3145728;          // bf16 elems per layer
    const size_t need_all = ((size_t)(LW - (__bf16*)d_ws)) * 2 + DEPTH * LWSTRIDE * 2;
    const bool bigLW = ws_size >= need_all;

    // ---- stage-weight transpose+convert (per run) ----
    tconv_kernel<<<dim3(48, 3),  256, 0, stream>>>(s1_w1,  SW + 0,       128, 384);
    tconv_kernel<<<dim3(48, 3),  256, 0, stream>>>(s1_w2,  SW + 147456,  384, 128);
    tconv_kernel<<<dim3(192, 3), 256, 0, stream>>>(s2_w1,  SW + 294912,  256, 768);
    tconv_kernel<<<dim3(192, 3), 256, 0, stream>>>(s2_w2,  SW + 884736,  768, 256);
    tconv_kernel<<<dim3(128, 1), 256, 0, stream>>>(pm1_rw, SW + 1474560, 512, 256);
    tconv_kernel<<<dim3(512, 1), 256, 0, stream>>>(pm2_rw, SW + 1605632, 1024, 512);
    if (bigLW)
        layer_tconv_kernel<<<dim3(768, DEPTH), 256, 0, stream>>>(
            qkvw, projw, w1, w2, LW, LWSTRIDE);

    conv_ln_kernel<<<Bb*56*56, 128, 0, stream>>>(image, conv_w, conv_b, pn_g, pn_b, X);

    for (int t = 0; t < 3; ++t) {
        ln_kernel<<<25088/4, 256, 0, stream>>>(X, s1_ng + t*128, s1_nb + t*128, Y, 25088, 128);
        gemm_kernel<128, EPI_BIAS_GELU><<<dim3(3, 196), 256, 0, stream>>>(
            Y, SW + t*49152, s1_b1 + t*384, nullptr, H, 25088, 384, 128, 128);
        gemm_kernel<64, EPI_BIAS_RES><<<dim3(1, 392), 256, 0, stream>>>(
            H, SW + 147456 + t*49152, s1_b2 + t*128, X, X, 25088, 128, 384, 384);
    }
    merge1_ln_kernel<<<6272/4, 256, 0, stream>>>(X, pm1_ng, pm1_nb, Y);
    gemm64_kernel<EPI_NONE><<<dim3(4, 98), 256, 0, stream>>>(
        Y, SW + 1474560, nullptr, nullptr, X, 6272, 256, 512, 512);
    for (int t = 0; t < 3; ++t) {
        ln_kernel<<<6272/4, 256, 0, stream>>>(X, s2_ng + t*256, s2_nb + t*256, Y, 6272, 256);
        gemm_kernel<128, EPI_BIAS_GELU><<<dim3(6, 49), 256, 0, stream>>>(
            Y, SW + 294912 + t*196608, s2_b1 + t*768, nullptr, H, 6272, 768, 256, 256);
        gemm_kernel<64, EPI_BIAS_RES><<<dim3(2, 98), 256, 0, stream>>>(
            H, SW + 884736 + t*196608, s2_b2 + t*256, X, X, 6272, 256, 768, 768);
    }
    merge2_ln_kernel<<<1568/4, 256, 0, stream>>>(X, pm2_ng, pm2_nb, Y);
    // merge2 projection with fused ape-add epilogue
    gemm64_kernel<EPI_APE><<<dim3(8, 25), 256, 0, stream>>>(
        Y, SW + 1605632, nullptr, ape, X, 1568, 512, 1024, 1024);

    for (int l = 0; l < DEPTH; ++l) {
        const __bf16* LWl = bigLW ? LW + (size_t)l * LWSTRIDE : LW;
        if (!bigLW)
            layer_tconv_kernel<<<dim3(768, 1), 256, 0, stream>>>(
                qkvw + (size_t)l*512*1536, projw + (size_t)l*512*512,
                w1 + (size_t)l*512*2048, w2 + (size_t)l*2048*512, LW, 0);
        ln_kernel<<<392, 256, 0, stream>>>(X, n1g + l*EMB, n1b + l*EMB, Y, 1568, EMB);
        // qkv: single-pass, bf16 direct write, 600 blocks
        gemm64_kernel<EPI_BIAS><<<dim3(24, 25), 256, 0, stream>>>(
            Y, LWl, qkvb + (size_t)l*1536, nullptr, H, 1568, 1536, EMB, EMB);
        attn_kernel<<<256, 256, 0, stream>>>(H, tab + (size_t)l*RPEL*HEADS, rpe, Y);
        // proj: split-K x4, atomic onto residual X (res-add free), 800 blocks
        gemm64_kernel<EPI_ATOMIC><<<dim3(8, 25, 4), 256, 0, stream>>>(
            Y, LWl + 786432, projb + (size_t)l*EMB, nullptr, X, 1568, EMB, EMB, 128);
        ln_kernel<<<392, 256, 0, stream>>>(X, n2g + l*EMB, n2b + l*EMB, Y, 1568, EMB);
        // mlp1: full-K (GELU epilogue needs full sum), 800 blocks
        gemm64_kernel<EPI_BIAS_GELU><<<dim3(32, 25), 256, 0, stream>>>(
            Y, LWl + 1048576, b1 + (size_t)l*2048, nullptr, H, 1568, 2048, EMB, EMB);
        // mlp2: split-K x4, atomic onto residual X, 800 blocks
        gemm64_kernel<EPI_ATOMIC><<<dim3(8, 25, 4), 256, 0, stream>>>(
            H, LWl + 2097152, b2 + (size_t)l*EMB, nullptr, X, 1568, EMB, 2048, 512);
    }
    hipMemcpyAsync(d_out, X, (size_t)1568*512*sizeof(float), hipMemcpyDeviceToDevice, stream);
}

// Round 4
// 2807.507 us; speedup vs baseline: 1.0994x; 1.0003x over previous
//
#include <hip/hip_runtime.h>
#include <hip/hip_bf16.h>

// ---------------- constants ----------------
#define Bb    8
#define IMG   224
#define Hp    14
#define Np    196      // tokens per image
#define D4    128
#define D8    256
#define EMB   512
#define HEADS 8
#define RPEL  729
#define DEPTH 24
#define EPS   1e-5f

constexpr int EPI_NONE = 0, EPI_BIAS = 1, EPI_BIAS_GELU = 2, EPI_BIAS_RES = 3, EPI_ATOMIC = 4, EPI_APE = 5;

typedef __bf16 bf16x8 __attribute__((ext_vector_type(8)));
typedef float  f32x4  __attribute__((ext_vector_type(4)));

// async global->LDS, 16B per lane. LDS dest = wave-uniform base + lane*16.
static __device__ __forceinline__ void gload16(const void* g, void* l) {
    __builtin_amdgcn_global_load_lds(
        (const __attribute__((address_space(1))) void*)g,
        (__attribute__((address_space(3))) void*)l, 16, 0, 0);
}

// ================= conv 4x4/4 + patchify + per-pixel LN =================
__global__ __launch_bounds__(128) void conv_ln_kernel(
    const float* __restrict__ img, const float* __restrict__ cw,
    const float* __restrict__ cb,  const float* __restrict__ png,
    const float* __restrict__ pnb, float* __restrict__ xout)
{
    int p = blockIdx.x;                 // b*3136 + h'*56 + w'
    int b = p / 3136, rem = p % 3136;
    int hh = rem / 56, ww = rem % 56;
    __shared__ float win[48];
    __shared__ float red[4];
    int t = threadIdx.x;
    if (t < 48) {
        int ic = t >> 4, kh = (t >> 2) & 3, kw = t & 3;
        win[t] = img[(((size_t)b*3 + ic)*224 + hh*4 + kh)*224 + ww*4 + kw];
    }
    __syncthreads();
    float acc = cb[t];
    const float* wrow = cw + (size_t)t * 48;
    #pragma unroll
    for (int r = 0; r < 48; ++r) acc += win[r] * wrow[r];
    float s = acc, ss = acc * acc;
    #pragma unroll
    for (int o = 32; o > 0; o >>= 1) { s += __shfl_xor(s, o, 64); ss += __shfl_xor(ss, o, 64); }
    int wv = t >> 6;
    if ((t & 63) == 0) { red[wv*2] = s; red[wv*2+1] = ss; }
    __syncthreads();
    s = red[0] + red[2]; ss = red[1] + red[3];
    float mean = s * (1.f/128.f);
    float rstd = rsqrtf(ss * (1.f/128.f) - mean*mean + EPS);
    float v = (acc - mean) * rstd * png[t] + pnb[t];
    int hp = hh >> 2, ih = hh & 3, wp = ww >> 2, iw = ww & 3;
    int bn = b * Np + hp * Hp + wp;
    xout[((size_t)bn*16 + ih*4 + iw)*128 + t] = v;
}

// ================= generic LayerNorm: one wave per row, f32 in -> bf16 out =================
__global__ __launch_bounds__(256) void ln_kernel(
    const float* __restrict__ x, const float* __restrict__ g,
    const float* __restrict__ b, __bf16* __restrict__ y, int M, int D)
{
    int wave = threadIdx.x >> 6, lane = threadIdx.x & 63;
    int row = blockIdx.x * 4 + wave;
    if (row >= M) return;
    const float* xr = x + (size_t)row * D;
    float s = 0.f, ss = 0.f;
    for (int i = lane; i < D; i += 64) { float v = xr[i]; s += v; ss += v*v; }
    #pragma unroll
    for (int o = 32; o > 0; o >>= 1) { s += __shfl_xor(s, o, 64); ss += __shfl_xor(ss, o, 64); }
    float inv = 1.f / (float)D;
    float mean = s * inv;
    float rstd = rsqrtf(ss * inv - mean*mean + EPS);
    __bf16* yr = y + (size_t)row * D;
    for (int i = lane; i < D; i += 64)
        yr[i] = (__bf16)((xr[i] - mean) * rstd * g[i] + b[i]);
}

// ================= merge1: gather 2x2 inner (dim128->512) + LN =================
__global__ __launch_bounds__(256) void merge1_ln_kernel(
    const float* __restrict__ x, const float* __restrict__ g,
    const float* __restrict__ b, __bf16* __restrict__ y)
{
    int wave = threadIdx.x >> 6, lane = threadIdx.x & 63;
    int row = blockIdx.x * 4 + wave;
    if (row >= 6272) return;
    int j2 = row & 1, i2 = (row >> 1) & 1, bn = row >> 2;
    float vals[8]; float s = 0.f, ss = 0.f;
    #pragma unroll
    for (int t = 0; t < 8; ++t) {
        int e = lane + t*64;
        int k = e >> 7, c = e & 127;
        int ih = 2*i2 + (k & 1), iw = 2*j2 + (k >> 1);
        float v = x[((size_t)bn*16 + ih*4 + iw)*128 + c];
        vals[t] = v; s += v; ss += v*v;
    }
    #pragma unroll
    for (int o = 32; o > 0; o >>= 1) { s += __shfl_xor(s, o, 64); ss += __shfl_xor(ss, o, 64); }
    float mean = s * (1.f/512.f);
    float rstd = rsqrtf(ss * (1.f/512.f) - mean*mean + EPS);
    __bf16* yr = y + (size_t)row * 512;
    #pragma unroll
    for (int t = 0; t < 8; ++t) {
        int e = lane + t*64;
        yr[e] = (__bf16)((vals[t] - mean) * rstd * g[e] + b[e]);
    }
}

// ================= merge2: gather 2x2 tokens (dim256->1024) + LN =================
__global__ __launch_bounds__(256) void merge2_ln_kernel(
    const float* __restrict__ x, const float* __restrict__ g,
    const float* __restrict__ b, __bf16* __restrict__ y)
{
    int wave = threadIdx.x >> 6, lane = threadIdx.x & 63;
    int row = blockIdx.x * 4 + wave;
    if (row >= 1568) return;
    float vals[16]; float s = 0.f, ss = 0.f;
    #pragma unroll
    for (int t = 0; t < 16; ++t) {
        int e = lane + t*64;
        int k = e >> 8, c = e & 255;
        float v = x[((size_t)row*4 + (k & 1)*2 + (k >> 1))*256 + c];
        vals[t] = v; s += v; ss += v*v;
    }
    #pragma unroll
    for (int o = 32; o > 0; o >>= 1) { s += __shfl_xor(s, o, 64); ss += __shfl_xor(ss, o, 64); }
    float mean = s * (1.f/1024.f);
    float rstd = rsqrtf(ss * (1.f/1024.f) - mean*mean + EPS);
    __bf16* yr = y + (size_t)row * 1024;
    #pragma unroll
    for (int t = 0; t < 16; ++t) {
        int e = lane + t*64;
        yr[e] = (__bf16)((vals[t] - mean) * rstd * g[e] + b[e]);
    }
}

// ================= transpose+convert 32x32: f32 [R][C] -> bf16 [C][R] =================
static __device__ __forceinline__ void tconv_tile(
    const float* __restrict__ in, __bf16* __restrict__ out,
    int R, int C, int tile, float (*t)[33])
{
    int tiles_c = C >> 5;
    int tr = tile / tiles_c, tc = tile - tr * tiles_c;
    int ty = threadIdx.x >> 3, tx = threadIdx.x & 7;
    const float4 v = *(const float4*)&in[(size_t)(tr*32 + ty) * C + (tc*32 + tx*4)];
    t[ty][tx*4+0] = v.x; t[ty][tx*4+1] = v.y; t[ty][tx*4+2] = v.z; t[ty][tx*4+3] = v.w;
    __syncthreads();
    __bf16 o[4];
    #pragma unroll
    for (int j = 0; j < 4; ++j) o[j] = (__bf16)t[tx*4+j][ty];
    *(uint2*)&out[(size_t)(tc*32 + ty) * R + (tr*32 + tx*4)] = *(const uint2*)o;
}

__global__ __launch_bounds__(256) void tconv_kernel(
    const float* __restrict__ in, __bf16* __restrict__ out, int R, int C)
{
    __shared__ float t[32][33];
    size_t off = (size_t)blockIdx.y * R * C;
    tconv_tile(in + off, out + off, R, C, blockIdx.x, t);
}

// ================= transpose+convert 64x64 (coalesced 128B-row writes) =================
static __device__ __forceinline__ void tconv64_tile(
    const float* __restrict__ in, __bf16* __restrict__ out,
    int R, int C, int tile, float (*t)[65])
{
    int tiles_c = C >> 6;
    int tr = tile / tiles_c, tc = tile - tr * tiles_c;
    int tid = threadIdx.x;
    int lrow = tid >> 4, lcol = (tid & 15) << 2;
    #pragma unroll
    for (int i = 0; i < 4; ++i) {
        int row = lrow + i*16;
        const float4 v = *(const float4*)&in[(size_t)(tr*64 + row) * C + (tc*64 + lcol)];
        t[row][lcol+0] = v.x; t[row][lcol+1] = v.y; t[row][lcol+2] = v.z; t[row][lcol+3] = v.w;
    }
    __syncthreads();
    int orow = tid >> 3, och = tid & 7;
    #pragma unroll
    for (int i = 0; i < 2; ++i) {
        int r = orow + i*32;
        __bf16 o[8];
        #pragma unroll
        for (int j = 0; j < 8; ++j) o[j] = (__bf16)t[och*8 + j][r];
        *(uint4*)&out[(size_t)(tc*64 + r) * R + (tr*64 + och*8)] = *(const uint4*)o;
    }
}

// all 4 weight matrices of one transformer layer (blockIdx.y = layer), 768 tiles
__global__ __launch_bounds__(256) void layer_tconv_kernel(
    const float* __restrict__ qkvw, const float* __restrict__ projw,
    const float* __restrict__ w1, const float* __restrict__ w2,
    __bf16* __restrict__ LW, size_t lw_stride)
{
    __shared__ float t[64][65];
    int l = blockIdx.y;
    int b = blockIdx.x;
    const float* q_ = qkvw  + (size_t)l * 786432;
    const float* p_ = projw + (size_t)l * 262144;
    const float* a_ = w1    + (size_t)l * 1048576;
    const float* c_ = w2    + (size_t)l * 1048576;
    __bf16* o = LW + (size_t)l * lw_stride;
    if (b < 192)       tconv64_tile(q_, o,           512, 1536, b,       t);
    else if (b < 256)  tconv64_tile(p_, o +  786432, 512,  512, b - 192, t);
    else if (b < 512)  tconv64_tile(a_, o + 1048576, 512, 2048, b - 256, t);
    else               tconv64_tile(c_, o + 2097152, 2048, 512, b - 512, t);
}

// ================= MFMA GEMM (BN=128, BK=32), 2-phase pipelined =================
// T3 recipe: STAGE(t+1) -> ds_read/MFMA on buf[cur] -> vmcnt(0) -> ONE s_barrier.
// Prefetch latency hides under compute; single barrier per tile is sound because
// each wave's lgkm waits (before MFMA) guarantee its reads of buf[cur] completed
// before it arrives at the barrier, so iter t+1 may overwrite buf[cur].
template<int BM, int EPI>
__global__ __launch_bounds__(256) void gemm_kernel(
    const __bf16* __restrict__ A, const __bf16* __restrict__ Bt,
    const float* __restrict__ bias, const float* __restrict__ Rres,
    void* __restrict__ Cv, int M, int N, int K, int kChunk)
{
    constexpr int BF = (BM == 128) ? 4 : 2;      // b-frags per wave
    constexpr int ABYTES = BM * 64;              // one A buffer (BM x 32 bf16)
    constexpr int BBYTES = 8192;                 // one B buffer (128 x 32 bf16)
    __shared__ __bf16 As[2][BM][32];             // linear (gload_lds needs it)
    __shared__ __bf16 Bs[2][128][32];
    const int tid = threadIdx.x, lane = tid & 63, wave = tid >> 6;
    const int m0 = blockIdx.y * BM, n0 = blockIdx.x << 7;
    int wm, wn;
    if constexpr (BM == 128) { wm = (wave >> 1) << 6; wn = (wave & 1) << 6; }
    else                     { wm = 0;                wn = wave << 5;       }
    const int q = lane >> 4, mr = lane & 15;
    const int kstart = blockIdx.z * kChunk;
    const int kend   = min(kstart + kChunk, K);

    f32x4 acc[4][BF];
    #pragma unroll
    for (int i = 0; i < 4; ++i)
        #pragma unroll
        for (int j = 0; j < BF; ++j)
            acc[i][j] = (f32x4){0.f, 0.f, 0.f, 0.f};

    const int crow = tid >> 2, ccol = (tid & 3) << 3;
    const __bf16* ag0 = A + (size_t)min(m0 + crow, M - 1) * K + ccol;
    const __bf16* ag1 = ag0;
    if constexpr (BM == 128)
        ag1 = A + (size_t)min(m0 + 64 + crow, M - 1) * K + ccol;
    const __bf16* bg0 = Bt + (size_t)(n0 + crow) * K + ccol;
    const __bf16* bg1 = Bt + (size_t)(n0 + 64 + crow) * K + ccol;
    char* lA = (char*)&As[0][0][0] + wave * 1024;   // wave-uniform segment base
    char* lB = (char*)&Bs[0][0][0] + wave * 1024;

#define STAGEB(k0_, buf_) do {                                        \
        gload16(ag0 + (k0_), lA + (buf_) * ABYTES);                   \
        if constexpr (BM == 128)                                      \
            gload16(ag1 + (k0_), lA + (buf_) * ABYTES + 4096);        \
        gload16(bg0 + (k0_), lB + (buf_) * BBYTES);                   \
        gload16(bg1 + (k0_), lB + (buf_) * BBYTES + 4096);            \
    } while (0)

    STAGEB(kstart, 0);
    asm volatile("s_waitcnt vmcnt(0)" ::: "memory");
    __builtin_amdgcn_s_barrier();
    int cur = 0;
    for (int k0 = kstart; k0 < kend; k0 += 32) {
        if (k0 + 32 < kend) STAGEB(k0 + 32, cur ^ 1);
        bf16x8 af[4], bfr[BF];
        #pragma unroll
        for (int i = 0; i < 4; ++i)
            af[i] = *(const bf16x8*)&As[cur][wm + i*16 + mr][q*8];
        #pragma unroll
        for (int j = 0; j < BF; ++j)
            bfr[j] = *(const bf16x8*)&Bs[cur][wn + j*16 + mr][q*8];
        #pragma unroll
        for (int i = 0; i < 4; ++i)
            #pragma unroll
            for (int j = 0; j < BF; ++j)
                acc[i][j] = __builtin_amdgcn_mfma_f32_16x16x32_bf16(af[i], bfr[j], acc[i][j], 0, 0, 0);
        asm volatile("s_waitcnt vmcnt(0)" ::: "memory");  // next tile landed (hidden under MFMA)
        __builtin_amdgcn_s_barrier();
        cur ^= 1;
    }
#undef STAGEB

    const bool addb = (blockIdx.z == 0);
    #pragma unroll
    for (int i = 0; i < 4; ++i) {
        #pragma unroll
        for (int j = 0; j < BF; ++j) {
            const int n = n0 + wn + j*16 + mr;
            float bv = 0.f;
            if constexpr (EPI != EPI_NONE) bv = bias[n];
            #pragma unroll
            for (int r = 0; r < 4; ++r) {
                const int m = m0 + wm + i*16 + q*4 + r;
                if (m < M) {
                    if constexpr (EPI == EPI_ATOMIC) {
                        atomicAdd(&((float*)Cv)[(size_t)m * N + n], acc[i][j][r] + (addb ? bv : 0.f));
                    } else {
                        float v = acc[i][j][r] + bv;
                        if constexpr (EPI == EPI_BIAS_GELU)
                            v = 0.5f * v * (1.f + erff(v * 0.70710678118654752f));
                        if constexpr (EPI == EPI_BIAS_RES)
                            v += Rres[(size_t)m * N + n];
                        if constexpr (EPI == EPI_BIAS || EPI == EPI_BIAS_GELU)
                            ((__bf16*)Cv)[(size_t)m * N + n] = (__bf16)v;
                        else
                            ((float*)Cv)[(size_t)m * N + n] = v;
                    }
                }
            }
        }
    }
}

// ================= small-M MFMA GEMM: 64x64 tile, BK=64, XOR-swizzled, 2-phase =================
// Same T3 pipeline as above. LDS rows are 128B (16-way conflict raw); fixed by the
// m201/m173 both-sides XOR: pre-swizzled GLOBAL source col, linear gload_lds dest,
// same XOR on the ds_read col. 2-way residual conflict = free (m136).
template<int EPI>
__global__ __launch_bounds__(256) void gemm64_kernel(
    const __bf16* __restrict__ A, const __bf16* __restrict__ Bt,
    const float* __restrict__ bias, const float* __restrict__ Rres,
    void* __restrict__ Cv, int M, int N, int K, int kChunk)
{
    __shared__ __bf16 As[2][64][64];    // 2 x 8 KB
    __shared__ __bf16 Bs[2][64][64];    // 2 x 8 KB
    const int tid = threadIdx.x, lane = tid & 63, wave = tid >> 6;
    const int m0 = blockIdx.y << 6, n0 = blockIdx.x << 6;
    const int wm = (wave >> 1) << 5, wn = (wave & 1) << 5;
    const int q = lane >> 4, mr = lane & 15;
    const int kstart = blockIdx.z * kChunk;
    const int kend   = min(kstart + kChunk, K);

    f32x4 acc[2][2];
    #pragma unroll
    for (int i = 0; i < 2; ++i)
        #pragma unroll
        for (int j = 0; j < 2; ++j)
            acc[i][j] = (f32x4){0.f, 0.f, 0.f, 0.f};

    // staging: slot s = tid + 256*i -> row = s>>3, col8 = s&7 (16B each)
    const int srow = tid >> 3;                       // 0..31 (slot1 adds 32)
    const int scol = ((tid & 7) << 3) ^ ((srow & 7) << 3);   // pre-swizzled source col
    const __bf16* agA = A  + (size_t)min(m0 + srow,      M - 1) * K + scol;
    const __bf16* agB = A  + (size_t)min(m0 + 32 + srow, M - 1) * K + scol;
    const __bf16* bgA = Bt + (size_t)(n0 + srow)      * K + scol;
    const __bf16* bgB = Bt + (size_t)(n0 + 32 + srow) * K + scol;
    char* lA = (char*)&As[0][0][0] + wave * 1024;    // wave-uniform segment base
    char* lB = (char*)&Bs[0][0][0] + wave * 1024;

    // swizzled read col-groups (bytes within a 128B row), h=0 / h=1 k-halves
    const int pg0 = ((q)     ^ (mr & 7)) << 4;
    const int pg1 = ((q + 4) ^ (mr & 7)) << 4;

#define STAGE64(k0_, buf_) do {                                       \
        gload16(agA + (k0_), lA + (buf_) * 8192);                     \
        gload16(agB + (k0_), lA + (buf_) * 8192 + 4096);              \
        gload16(bgA + (k0_), lB + (buf_) * 8192);                     \
        gload16(bgB + (k0_), lB + (buf_) * 8192 + 4096);              \
    } while (0)

    STAGE64(kstart, 0);
    asm volatile("s_waitcnt vmcnt(0)" ::: "memory");
    __builtin_amdgcn_s_barrier();
    int cur = 0;
    for (int k0 = kstart; k0 < kend; k0 += 64) {
        if (k0 + 64 < kend) STAGE64(k0 + 64, cur ^ 1);
        bf16x8 af[2][2], bfr[2][2];
        #pragma unroll
        for (int i = 0; i < 2; ++i) {
            const char* ar = (const char*)&As[cur][wm + i*16 + mr][0];
            af[i][0] = *(const bf16x8*)(ar + pg0);
            af[i][1] = *(const bf16x8*)(ar + pg1);
        }
        #pragma unroll
        for (int j = 0; j < 2; ++j) {
            const char* br = (const char*)&Bs[cur][wn + j*16 + mr][0];
            bfr[j][0] = *(const bf16x8*)(br + pg0);
            bfr[j][1] = *(const bf16x8*)(br + pg1);
        }
        #pragma unroll
        for (int i = 0; i < 2; ++i)
            #pragma unroll
            for (int j = 0; j < 2; ++j) {
                acc[i][j] = __builtin_amdgcn_mfma_f32_16x16x32_bf16(af[i][0], bfr[j][0], acc[i][j], 0, 0, 0);
                acc[i][j] = __builtin_amdgcn_mfma_f32_16x16x32_bf16(af[i][1], bfr[j][1], acc[i][j], 0, 0, 0);
            }
        asm volatile("s_waitcnt vmcnt(0)" ::: "memory");  // next tile landed (hidden under MFMA)
        __builtin_amdgcn_s_barrier();
        cur ^= 1;
    }
#undef STAGE64

    const bool addb = (blockIdx.z == 0);
    #pragma unroll
    for (int i = 0; i < 2; ++i) {
        #pragma unroll
        for (int j = 0; j < 2; ++j) {
            const int n = n0 + wn + j*16 + mr;
            float bv = 0.f;
            if constexpr (EPI == EPI_BIAS || EPI == EPI_BIAS_GELU || EPI == EPI_BIAS_RES || EPI == EPI_ATOMIC)
                bv = bias[n];
            #pragma unroll
            for (int r = 0; r < 4; ++r) {
                const int m = m0 + wm + i*16 + q*4 + r;
                if (m < M) {
                    if constexpr (EPI == EPI_ATOMIC) {
                        atomicAdd(&((float*)Cv)[(size_t)m * N + n], acc[i][j][r] + (addb ? bv : 0.f));
                    } else {
                        float v = acc[i][j][r] + bv;
                        if constexpr (EPI == EPI_BIAS_GELU)
                            v = 0.5f * v * (1.f + erff(v * 0.70710678118654752f));
                        if constexpr (EPI == EPI_BIAS_RES)
                            v += Rres[(size_t)m * N + n];
                        if constexpr (EPI == EPI_APE)
                            v += Rres[(size_t)(m % Np) * N + n];   // ape broadcast over batch
                        if constexpr (EPI == EPI_BIAS || EPI == EPI_BIAS_GELU)
                            ((__bf16*)Cv)[(size_t)m * N + n] = (__bf16)v;
                        else
                            ((float*)Cv)[(size_t)m * N + n] = v;
                    }
                }
            }
        }
    }
}

// ================= MFMA fused attention (bf16 qkv input, bias via rpe gather) =================
__global__ __launch_bounds__(256) void attn_kernel(
    const __bf16* __restrict__ qkv, const float* __restrict__ tab,
    const int* __restrict__ rpe, __bf16* __restrict__ y2)
{
    __shared__ __bf16 Vt[64][232];        // V^T: [d][key]
    __shared__ __bf16 Pl[4][16][232];     // per-wave P tile [qrow][key]
    int blk = blockIdx.x;                 // b*32 + h*4 + qg
    int qg = blk & 3, h = (blk >> 2) & 7, b = blk >> 5;
    int tid = threadIdx.x;

    // ---- stage V transposed ----
    for (int i = tid; i < 196*8; i += 256) {
        int key = i >> 3, seg = i & 7;
        bf16x8 v = *(const bf16x8*)(qkv + ((size_t)(b*Np + key))*1536 + 1024 + h*64 + seg*8);
        #pragma unroll
        for (int j = 0; j < 8; ++j) Vt[seg*8 + j][key] = v[j];
    }
    {
        int d0 = tid >> 2, cs = tid & 3;
        #pragma unroll
        for (int j = 0; j < 9; ++j) Vt[d0][196 + cs*9 + j] = (__bf16)0.f;
    }
    __syncthreads();

    int lane = tid & 63, wave = tid >> 6;
    int T = qg + 4*wave;
    if (T > 12) return;
    int q = lane >> 4, mr = lane & 15;

    if (lane < 36) {
        #pragma unroll
        for (int r = 0; r < 16; ++r) Pl[wave][r][196 + lane] = (__bf16)0.f;
    }

    // ---- Q fragments ----
    int qtok = b*Np + min(T*16 + mr, 195);
    const __bf16* qp = qkv + (size_t)qtok*1536 + h*64 + q*8;
    bf16x8 aq0 = *(const bf16x8*)qp;
    bf16x8 aq1 = *(const bf16x8*)(qp + 32);

    // ---- S = Q @ K^T ----
    f32x4 sacc[13];
    #pragma unroll
    for (int nt = 0; nt < 13; ++nt) {
        int ktok = b*Np + min(nt*16 + mr, 195);
        const __bf16* kp = qkv + (size_t)ktok*1536 + 512 + h*64 + q*8;
        bf16x8 bk0 = *(const bf16x8*)kp;
        bf16x8 bk1 = *(const bf16x8*)(kp + 32);
        f32x4 z = (f32x4){0.f, 0.f, 0.f, 0.f};
        z = __builtin_amdgcn_mfma_f32_16x16x32_bf16(aq0, bk0, z, 0, 0, 0);
        sacc[nt] = __builtin_amdgcn_mfma_f32_16x16x32_bf16(aq1, bk1, z, 0, 0, 0);
    }

    // ---- bias + softmax per row ----
    #pragma unroll
    for (int r = 0; r < 4; ++r) {
        int qi = T*16 + q*4 + r;
        const int* rrow = rpe + (size_t)min(qi, 195) * 196;
        float vals[13];
        #pragma unroll
        for (int nt = 0; nt < 13; ++nt) {
            int col = nt*16 + mr;
            float bv = tab[rrow[min(col, 195)]*8 + h];
            float v = sacc[nt][r] * 0.125f + bv;
            vals[nt] = (col < 196) ? v : -3.0e38f;
        }
        float m = vals[0];
        #pragma unroll
        for (int nt = 1; nt < 13; ++nt) m = fmaxf(m, vals[nt]);
        #pragma unroll
        for (int o = 8; o > 0; o >>= 1) m = fmaxf(m, __shfl_xor(m, o, 64));
        float s = 0.f, p[13];
        #pragma unroll
        for (int nt = 0; nt < 13; ++nt) { p[nt] = __expf(vals[nt] - m); s += p[nt]; }
        #pragma unroll
        for (int o = 8; o > 0; o >>= 1) s += __shfl_xor(s, o, 64);
        float inv = 1.f / s;
        #pragma unroll
        for (int nt = 0; nt < 13; ++nt)
            Pl[wave][q*4 + r][nt*16 + mr] = (__bf16)(p[nt] * inv);
    }

    // ---- O = P @ V ----
    f32x4 oacc[4];
    #pragma unroll
    for (int nt = 0; nt < 4; ++nt) oacc[nt] = (f32x4){0.f, 0.f, 0.f, 0.f};
    #pragma unroll
    for (int ks = 0; ks < 7; ++ks) {
        bf16x8 ap = *(const bf16x8*)&Pl[wave][mr][ks*32 + q*8];
        #pragma unroll
        for (int nt = 0; nt < 4; ++nt) {
            bf16x8 bv = *(const bf16x8*)&Vt[nt*16 + mr][ks*32 + q*8];
            oacc[nt] = __builtin_amdgcn_mfma_f32_16x16x32_bf16(ap, bv, oacc[nt], 0, 0, 0);
        }
    }

    #pragma unroll
    for (int nt = 0; nt < 4; ++nt) {
        #pragma unroll
        for (int r = 0; r < 4; ++r) {
            int qi = T*16 + q*4 + r;
            if (qi < 196)
                y2[((size_t)(b*Np + qi))*512 + h*64 + nt*16 + mr] = (__bf16)oacc[nt][r];
        }
    }
}

// ================= launcher =================
extern "C" void kernel_launch(void* const* d_in, const int* in_sizes, int n_in,
                              void* d_out, int out_size, void* d_ws, size_t ws_size,
                              hipStream_t stream)
{
    typedef const float* fp;
    fp image  = (fp)d_in[0];
    fp conv_w = (fp)d_in[1];  fp conv_b = (fp)d_in[2];
    fp pn_g   = (fp)d_in[3];  fp pn_b   = (fp)d_in[4];
    fp s1_ng  = (fp)d_in[5];  fp s1_nb  = (fp)d_in[6];
    fp s1_w1  = (fp)d_in[7];  fp s1_b1  = (fp)d_in[8];
    fp s1_w2  = (fp)d_in[9];  fp s1_b2  = (fp)d_in[10];
    fp s2_ng  = (fp)d_in[11]; fp s2_nb  = (fp)d_in[12];
    fp s2_w1  = (fp)d_in[13]; fp s2_b1  = (fp)d_in[14];
    fp s2_w2  = (fp)d_in[15]; fp s2_b2  = (fp)d_in[16];
    fp pm1_ng = (fp)d_in[17]; fp pm1_nb = (fp)d_in[18]; fp pm1_rw = (fp)d_in[19];
    fp pm2_ng = (fp)d_in[20]; fp pm2_nb = (fp)d_in[21]; fp pm2_rw = (fp)d_in[22];
    fp ape    = (fp)d_in[23];
    fp n1g    = (fp)d_in[24]; fp n1b    = (fp)d_in[25];
    fp qkvw   = (fp)d_in[26]; fp qkvb   = (fp)d_in[27];
    fp tab    = (fp)d_in[28];
    fp projw  = (fp)d_in[29]; fp projb  = (fp)d_in[30];
    fp n2g    = (fp)d_in[31]; fp n2b    = (fp)d_in[32];
    fp w1     = (fp)d_in[33]; fp b1     = (fp)d_in[34];
    fp w2     = (fp)d_in[35]; fp b2     = (fp)d_in[36];
    const int* rpe = (const int*)d_in[37];

    float*  X  = (float*)d_ws;                // 3,211,264 f32 residual
    __bf16* H  = (__bf16*)(X + 3211264);      // 9,633,792 bf16 hidden (mlp hidden / qkv)
    __bf16* Y  = H + 9633792;                 // 3,211,264 bf16 LN out / attn out
    __bf16* SW = Y + 3211264;                 // 2,129,920 bf16 stage weights (B^T)
    __bf16* LW = SW + 2129920;                // per-layer (or all-layer) bf16 weights (B^T)

    // all-layer weight hoist if workspace permits (194 MB); else per-layer (49 MB)
    const size_t LWSTRIDE = 3145728;          // bf16 elems per layer
    const size_t need_all = ((size_t)(LW - (__bf16*)d_ws)) * 2 + DEPTH * LWSTRIDE * 2;
    const bool bigLW = ws_size >= need_all;

    // ---- stage-weight transpose+convert (per run) ----
    tconv_kernel<<<dim3(48, 3),  256, 0, stream>>>(s1_w1,  SW + 0,       128, 384);
    tconv_kernel<<<dim3(48, 3),  256, 0, stream>>>(s1_w2,  SW + 147456,  384, 128);
    tconv_kernel<<<dim3(192, 3), 256, 0, stream>>>(s2_w1,  SW + 294912,  256, 768);
    tconv_kernel<<<dim3(192, 3), 256, 0, stream>>>(s2_w2,  SW + 884736,  768, 256);
    tconv_kernel<<<dim3(128, 1), 256, 0, stream>>>(pm1_rw, SW + 1474560, 512, 256);
    tconv_kernel<<<dim3(512, 1), 256, 0, stream>>>(pm2_rw, SW + 1605632, 1024, 512);
    if (bigLW)
        layer_tconv_kernel<<<dim3(768, DEPTH), 256, 0, stream>>>(
            qkvw, projw, w1, w2, LW, LWSTRIDE);

    conv_ln_kernel<<<Bb*56*56, 128, 0, stream>>>(image, conv_w, conv_b, pn_g, pn_b, X);

    for (int t = 0; t < 3; ++t) {
        ln_kernel<<<25088/4, 256, 0, stream>>>(X, s1_ng + t*128, s1_nb + t*128, Y, 25088, 128);
        gemm_kernel<128, EPI_BIAS_GELU><<<dim3(3, 196), 256, 0, stream>>>(
            Y, SW + t*49152, s1_b1 + t*384, nullptr, H, 25088, 384, 128, 128);
        gemm_kernel<64, EPI_BIAS_RES><<<dim3(1, 392), 256, 0, stream>>>(
            H, SW + 147456 + t*49152, s1_b2 + t*128, X, X, 25088, 128, 384, 384);
    }
    merge1_ln_kernel<<<6272/4, 256, 0, stream>>>(X, pm1_ng, pm1_nb, Y);
    gemm64_kernel<EPI_NONE><<<dim3(4, 98), 256, 0, stream>>>(
        Y, SW + 1474560, nullptr, nullptr, X, 6272, 256, 512, 512);
    for (int t = 0; t < 3; ++t) {
        ln_kernel<<<6272/4, 256, 0, stream>>>(X, s2_ng + t*256, s2_nb + t*256, Y, 6272, 256);
        gemm_kernel<128, EPI_BIAS_GELU><<<dim3(6, 49), 256, 0, stream>>>(
            Y, SW + 294912 + t*196608, s2_b1 + t*768, nullptr, H, 6272, 768, 256, 256);
        gemm_kernel<64, EPI_BIAS_RES><<<dim3(2, 98), 256, 0, stream>>>(
            H, SW + 884736 + t*196608, s2_b2 + t*256, X, X, 6272, 256, 768, 768);
    }
    merge2_ln_kernel<<<1568/4, 256, 0, stream>>>(X, pm2_ng, pm2_nb, Y);
    // merge2 projection with fused ape-add epilogue
    gemm64_kernel<EPI_APE><<<dim3(8, 25), 256, 0, stream>>>(
        Y, SW + 1605632, nullptr, ape, X, 1568, 512, 1024, 1024);

    for (int l = 0; l < DEPTH; ++l) {
        const __bf16* LWl = bigLW ? LW + (size_t)l * LWSTRIDE : LW;
        if (!bigLW)
            layer_tconv_kernel<<<dim3(768, 1), 256, 0, stream>>>(
                qkvw + (size_t)l*512*1536, projw + (size_t)l*512*512,
                w1 + (size_t)l*512*2048, w2 + (size_t)l*2048*512, LW, 0);
        ln_kernel<<<392, 256, 0, stream>>>(X, n1g + l*EMB, n1b + l*EMB, Y, 1568, EMB);
        // qkv: single-pass, bf16 direct write, 600 blocks
        gemm64_kernel<EPI_BIAS><<<dim3(24, 25), 256, 0, stream>>>(
            Y, LWl, qkvb + (size_t)l*1536, nullptr, H, 1568, 1536, EMB, EMB);
        attn_kernel<<<256, 256, 0, stream>>>(H, tab + (size_t)l*RPEL*HEADS, rpe, Y);
        // proj: split-K x4, atomic onto residual X (res-add free), 800 blocks
        gemm64_kernel<EPI_ATOMIC><<<dim3(8, 25, 4), 256, 0, stream>>>(
            Y, LWl + 786432, projb + (size_t)l*EMB, nullptr, X, 1568, EMB, EMB, 128);
        ln_kernel<<<392, 256, 0, stream>>>(X, n2g + l*EMB, n2b + l*EMB, Y, 1568, EMB);
        // mlp1: full-K (GELU epilogue needs full sum), 800 blocks
        gemm64_kernel<EPI_BIAS_GELU><<<dim3(32, 25), 256, 0, stream>>>(
            Y, LWl + 1048576, b1 + (size_t)l*2048, nullptr, H, 1568, 2048, EMB, EMB);
        // mlp2: split-K x4, atomic onto residual X, 800 blocks
        gemm64_kernel<EPI_ATOMIC><<<dim3(8, 25, 4), 256, 0, stream>>>(
            H, LWl + 2097152, b2 + (size_t)l*EMB, nullptr, X, 1568, EMB, 2048, 512);
    }
    hipMemcpyAsync(d_out, X, (size_t)1568*512*sizeof(float), hipMemcpyDeviceToDevice, stream);
}